// Round 3
// baseline (661.047 us; speedup 1.0000x reference)
//
#include <hip/hip_runtime.h>
#include <math.h>

// Problem constants
#define BB 32
#define NREC 64
#define CC 16
#define HW 63

// ---------------- Rectangle render ----------------
__global__ __launch_bounds__(256) void render_kernel(const float* __restrict__ x,
                                                     float* __restrict__ layout) {
    int bn = blockIdx.x;                 // b*NREC + n
    const float* xp = x + (size_t)bn * (4 + CC);
    __shared__ int cs[4];
    __shared__ float mps;
    if (threadIdx.x == 0) {
        cs[0] = (int)xp[0]; cs[1] = (int)xp[1];
        cs[2] = (int)xp[2]; cs[3] = (int)xp[3];
        float m = xp[4];
        #pragma unroll
        for (int c = 1; c < CC; ++c) m = fmaxf(m, xp[4 + c]);
        mps = m;
    }
    __syncthreads();
    int xL = cs[0], yT = cs[1], xR = cs[2], yB = cs[3];
    float m = mps;
    float* op = layout + (size_t)bn * HW * HW;
    for (int p = threadIdx.x; p < HW * HW; p += blockDim.x) {
        int u = p / HW, v = p % HW;
        bool vb = ((u == xL || u == xR) && (v > yT && v < yB)) ||
                  ((v == yT || v == yB) && (u > xL && u < xR));
        op[p] = vb ? m : 0.0f;
    }
}

// ---------------- Conv 3x3 stride-2 VALID, co-group per block ----------------
// Block = (b, output tile, group of COG output channels). Each thread: one
// output pixel, COG accumulators (ILP). Input staged in LDS in CICH-channel
// chunks with the previous layer's BN+ReLU fused at staging. Weights read via
// block-uniform indices (scalarized by compiler). Per-block BN partials via
// wave shuffle reduction.
template<int CIN, int COUT, int HIN, int HOUT, int TH, int TW, int NT,
         int COG, int CICH, bool FUSE>
__global__ __launch_bounds__(NT) void conv_kernel(
        const float* __restrict__ in,
        const float* __restrict__ scl,
        const float* __restrict__ shf,
        const float* __restrict__ w,     // [COUT][CIN][3][3]
        const float* __restrict__ bias,
        float* __restrict__ out,         // raw (pre-BN)
        float* __restrict__ psum,        // [COUT][PBLK]
        float* __restrict__ psq) {
    constexpr int TYT   = (HOUT + TH - 1) / TH;
    constexpr int TXT   = (HOUT + TW - 1) / TW;
    constexpr int TILES = TYT * TXT;
    constexpr int COGN  = COUT / COG;
    constexpr int ROWS  = 2 * TH + 1;
    constexpr int COLS  = 2 * TW + 1;
    constexpr int RS    = 2 * TW + 4;   // even row stride (float2 alignment)
    constexpr int PBLK  = BB * TILES;
    constexpr int NW    = NT / 64;

    __shared__ float lds[CICH * ROWS * RS];
    __shared__ float redbuf[2 * NW * COG];

    int tid = threadIdx.x;
    int bid = blockIdx.x;
    int cg   = bid % COGN;
    int tmp  = bid / COGN;
    int tile = tmp % TILES;
    int b    = tmp / TILES;
    int co0  = cg * COG;
    int ty0  = (tile / TXT) * TH;
    int tx0  = (tile % TXT) * TW;

    int ty = tid / TW, tx = tid % TW;
    int tyc = (ty < TH) ? ty : 0;
    int oy = ty0 + tyc, ox = tx0 + tx;
    bool active = (ty < TH) && (oy < HOUT) && (ox < HOUT);

    float acc[COG];
    #pragma unroll
    for (int i = 0; i < COG; ++i) acc[i] = 0.f;

    const float* inb0 = in + (size_t)b * CIN * HIN * HIN;

    for (int c0 = 0; c0 < CIN; c0 += CICH) {
        __syncthreads();
        // stage CICH input channels (with fused BN+ReLU if FUSE)
        const float* inb = inb0 + (size_t)c0 * HIN * HIN;
        for (int t = tid; t < CICH * ROWS * COLS; t += NT) {
            int cl = t / (ROWS * COLS);
            int rem = t % (ROWS * COLS);
            int r = rem / COLS, c = rem % COLS;
            int gy = 2 * ty0 + r, gx = 2 * tx0 + c;
            float v = (gy < HIN && gx < HIN) ? inb[cl * HIN * HIN + gy * HIN + gx] : 0.f;
            if (FUSE) v = fmaxf(fmaf(v, scl[c0 + cl], shf[c0 + cl]), 0.f);
            lds[cl * (ROWS * RS) + r * RS + c] = v;
        }
        __syncthreads();

        #pragma unroll
        for (int cl = 0; cl < CICH; ++cl) {
            const float* lrow = lds + cl * (ROWS * RS) + (2 * tyc) * RS + 2 * tx;
            float p[9];
            #pragma unroll
            for (int ky = 0; ky < 3; ++ky) {
                float2 ab = *(const float2*)(lrow + ky * RS);
                p[ky * 3 + 0] = ab.x;
                p[ky * 3 + 1] = ab.y;
                p[ky * 3 + 2] = lrow[ky * RS + 2];
            }
            int ci = c0 + cl;
            const float* wci = w + ((size_t)co0 * CIN + ci) * 9;
            #pragma unroll
            for (int i = 0; i < COG; ++i) {
                const float* wp = wci + (size_t)i * CIN * 9;  // uniform -> s_load
                float a = acc[i];
                a = fmaf(p[0], wp[0], a);
                a = fmaf(p[1], wp[1], a);
                a = fmaf(p[2], wp[2], a);
                a = fmaf(p[3], wp[3], a);
                a = fmaf(p[4], wp[4], a);
                a = fmaf(p[5], wp[5], a);
                a = fmaf(p[6], wp[6], a);
                a = fmaf(p[7], wp[7], a);
                a = fmaf(p[8], wp[8], a);
                acc[i] = a;
            }
        }
    }

    // epilogue: bias, write raw out, per-co partial stats
    float* outb = out + ((size_t)b * COUT + co0) * (HOUT * HOUT) + oy * HOUT + ox;
    #pragma unroll
    for (int i = 0; i < COG; ++i) {
        float v = active ? (acc[i] + bias[co0 + i]) : 0.f;
        if (active) outb[(size_t)i * (HOUT * HOUT)] = v;
        acc[i] = v;
    }

    int lane = tid & 63, wv = tid >> 6;
    #pragma unroll
    for (int i = 0; i < COG; ++i) {
        float s = acc[i], q = acc[i] * acc[i];
        #pragma unroll
        for (int o = 32; o > 0; o >>= 1) {
            s += __shfl_down(s, o, 64);
            q += __shfl_down(q, o, 64);
        }
        if (lane == 0) {
            redbuf[wv * COG + i] = s;
            redbuf[NW * COG + wv * COG + i] = q;
        }
    }
    __syncthreads();
    if (tid < COG) {
        float S = 0.f, Q = 0.f;
        #pragma unroll
        for (int v2 = 0; v2 < NW; ++v2) {
            S += redbuf[v2 * COG + tid];
            Q += redbuf[NW * COG + v2 * COG + tid];
        }
        int pb = b * TILES + tile;
        psum[(size_t)(co0 + tid) * PBLK + pb] = S;
        psq [(size_t)(co0 + tid) * PBLK + pb] = Q;
    }
}

// ---------------- Fold partials -> per-channel scale/shift ----------------
__global__ void stats_kernel(const float* __restrict__ psum, const float* __restrict__ psq,
                             const float* __restrict__ g, const float* __restrict__ be,
                             float* __restrict__ scale, float* __restrict__ shift,
                             int COUT, int PBLK, float count) {
    int c = threadIdx.x;
    if (c >= COUT) return;
    float s = 0.f, q = 0.f;
    for (int p = 0; p < PBLK; ++p) {
        s += psum[(size_t)c * PBLK + p];
        q += psq[(size_t)c * PBLK + p];
    }
    float mean = s / count;
    float var  = q / count - mean * mean;
    float sc   = g[c] * rsqrtf(var + 1e-5f);
    scale[c] = sc;
    shift[c] = be[c] - mean * sc;
}

// ---------------- FC1: one block per (b, j) ----------------
__global__ __launch_bounds__(256) void fc1_kernel(
        const float* __restrict__ out3,   // [B][128*49] raw
        const float* __restrict__ scale3, const float* __restrict__ shift3,
        const float* __restrict__ fc1w,   // [64][6272]
        const float* __restrict__ fc1b,
        float* __restrict__ h) {          // [B][64]
    const int FLAT = 128 * 49;
    int b = blockIdx.x >> 6;
    int j = blockIdx.x & 63;
    const float* ip = out3 + (size_t)b * FLAT;
    const float* wp = fc1w + (size_t)j * FLAT;
    float s = 0.f;
    for (int i = threadIdx.x; i < FLAT; i += 256) {
        int c = i / 49;
        float xv = fmaxf(fmaf(ip[i], scale3[c], shift3[c]), 0.f);
        s = fmaf(xv, wp[i], s);
    }
    #pragma unroll
    for (int o = 32; o > 0; o >>= 1) s += __shfl_down(s, o, 64);
    __shared__ float red[4];
    if ((threadIdx.x & 63) == 0) red[threadIdx.x >> 6] = s;
    __syncthreads();
    if (threadIdx.x == 0) {
        float t = red[0] + red[1] + red[2] + red[3];
        h[b * 64 + j] = fmaxf(t + fc1b[j], 0.f);
    }
}

// ---------------- FC2 + sigmoid ----------------
__global__ __launch_bounds__(64) void fc2_kernel(
        const float* __restrict__ h, const float* __restrict__ fc2w,
        const float* __restrict__ fc2b, float* __restrict__ outp) {
    int b = blockIdx.x;
    float v = h[b * 64 + threadIdx.x] * fc2w[threadIdx.x];
    #pragma unroll
    for (int o = 32; o > 0; o >>= 1) v += __shfl_down(v, o, 64);
    if (threadIdx.x == 0) outp[b] = 1.f / (1.f + expf(-(v + fc2b[0])));
}

// ---------------- Launch ----------------
extern "C" void kernel_launch(void* const* d_in, const int* in_sizes, int n_in,
                              void* d_out, int out_size, void* d_ws, size_t ws_size,
                              hipStream_t stream) {
    const float* x       = (const float*)d_in[0];
    const float* conv1_w = (const float*)d_in[1];
    const float* conv1_b = (const float*)d_in[2];
    const float* bn1_g   = (const float*)d_in[3];
    const float* bn1_b   = (const float*)d_in[4];
    const float* conv2_w = (const float*)d_in[5];
    const float* conv2_b = (const float*)d_in[6];
    const float* bn2_g   = (const float*)d_in[7];
    const float* bn2_b   = (const float*)d_in[8];
    const float* conv3_w = (const float*)d_in[9];
    const float* conv3_b = (const float*)d_in[10];
    const float* bn3_g   = (const float*)d_in[11];
    const float* bn3_b   = (const float*)d_in[12];
    const float* fc1_w   = (const float*)d_in[13];
    const float* fc1_b   = (const float*)d_in[14];
    const float* fc2_w   = (const float*)d_in[15];
    const float* fc2_b   = (const float*)d_in[16];
    float* out = (float*)d_out;

    float* ws = (float*)d_ws;
    size_t off = 0;
    float* layout = ws + off; off += (size_t)BB * NREC * HW * HW;
    float* out1   = ws + off; off += (size_t)BB * 64  * 31 * 31;
    float* out2   = ws + off; off += (size_t)BB * 128 * 15 * 15;
    float* out3   = ws + off; off += (size_t)BB * 128 * 7 * 7;
    float* psum1  = ws + off; off += 64 * 128;   // conv1: PBLK = 32*4
    float* psq1   = ws + off; off += 64 * 128;
    float* psum2  = ws + off; off += 128 * 32;
    float* psq2   = ws + off; off += 128 * 32;
    float* psum3  = ws + off; off += 128 * 32;
    float* psq3   = ws + off; off += 128 * 32;
    float* scale1 = ws + off; off += 64;
    float* shift1 = ws + off; off += 64;
    float* scale2 = ws + off; off += 128;
    float* shift2 = ws + off; off += 128;
    float* scale3 = ws + off; off += 128;
    float* shift3 = ws + off; off += 128;
    float* hbuf   = ws + off; off += BB * 64;

    render_kernel<<<BB * NREC, 256, 0, stream>>>(x, layout);

    // conv1: 63->31, tiles 2x2 of 16x16, co-groups of 16 -> grid 32*4*4 = 512
    conv_kernel<64, 64, 63, 31, 16, 16, 256, 16, 4, false>
        <<<32 * 4 * 4, 256, 0, stream>>>(layout, nullptr, nullptr,
                                         conv1_w, conv1_b, out1, psum1, psq1);
    stats_kernel<<<1, 64, 0, stream>>>(psum1, psq1, bn1_g, bn1_b, scale1, shift1,
                                       64, 32 * 4, (float)(BB * 31 * 31));

    // conv2: 31->15, single 15x15 tile, co-groups of 16 -> grid 32*8 = 256
    conv_kernel<64, 128, 31, 15, 15, 15, 256, 16, 4, true>
        <<<32 * 8, 256, 0, stream>>>(out1, scale1, shift1,
                                     conv2_w, conv2_b, out2, psum2, psq2);
    stats_kernel<<<1, 128, 0, stream>>>(psum2, psq2, bn2_g, bn2_b, scale2, shift2,
                                        128, 32, (float)(BB * 15 * 15));

    // conv3: 15->7, single 7x7 tile, co-groups of 16 -> grid 32*8 = 256
    conv_kernel<128, 128, 15, 7, 7, 7, 64, 16, 8, true>
        <<<32 * 8, 64, 0, stream>>>(out2, scale2, shift2,
                                    conv3_w, conv3_b, out3, psum3, psq3);
    stats_kernel<<<1, 128, 0, stream>>>(psum3, psq3, bn3_g, bn3_b, scale3, shift3,
                                        128, 32, (float)(BB * 7 * 7));

    fc1_kernel<<<BB * 64, 256, 0, stream>>>(out3, scale3, shift3, fc1_w, fc1_b, hbuf);
    fc2_kernel<<<BB, 64, 0, stream>>>(hbuf, fc2_w, fc2_b, out);
}

// Round 4
// 366.684 us; speedup vs baseline: 1.8028x; 1.8028x over previous
//
#include <hip/hip_runtime.h>
#include <math.h>

// Problem constants
#define BB 32
#define NREC 64
#define CC 16
#define HW 63

// ---------------- Rectangle render ----------------
__global__ __launch_bounds__(256) void render_kernel(const float* __restrict__ x,
                                                     float* __restrict__ layout) {
    int bn = blockIdx.x;                 // b*NREC + n
    const float* xp = x + (size_t)bn * (4 + CC);
    __shared__ int cs[4];
    __shared__ float mps;
    if (threadIdx.x == 0) {
        cs[0] = (int)xp[0]; cs[1] = (int)xp[1];
        cs[2] = (int)xp[2]; cs[3] = (int)xp[3];
        float m = xp[4];
        #pragma unroll
        for (int c = 1; c < CC; ++c) m = fmaxf(m, xp[4 + c]);
        mps = m;
    }
    __syncthreads();
    int xL = cs[0], yT = cs[1], xR = cs[2], yB = cs[3];
    float m = mps;
    float* op = layout + (size_t)bn * HW * HW;
    for (int p = threadIdx.x; p < HW * HW; p += blockDim.x) {
        int u = p / HW, v = p % HW;
        bool vb = ((u == xL || u == xR) && (v > yT && v < yB)) ||
                  ((v == yT || v == yB) && (u > xL && u < xR));
        op[p] = vb ? m : 0.0f;
    }
}

// ---------------- Conv 3x3 stride-2 VALID (conv1/conv2) ----------------
// Block = (b, tile, co-group of COG). Thread = one output pixel, COG
// independent accumulators. Input staged in LDS CICH channels at a time with
// previous layer's BN+ReLU fused at staging. Weights block-uniform -> s_load.
template<int CIN, int COUT, int HIN, int HOUT, int TH, int TW, int NT,
         int COG, int CICH, bool FUSE>
__global__ __launch_bounds__(NT) void conv_kernel(
        const float* __restrict__ in,
        const float* __restrict__ scl,
        const float* __restrict__ shf,
        const float* __restrict__ w,     // [COUT][CIN][3][3]
        const float* __restrict__ bias,
        float* __restrict__ out,         // raw (pre-BN)
        float* __restrict__ psum,        // [COUT][PBLK]
        float* __restrict__ psq) {
    constexpr int TYT   = (HOUT + TH - 1) / TH;
    constexpr int TXT   = (HOUT + TW - 1) / TW;
    constexpr int TILES = TYT * TXT;
    constexpr int COGN  = COUT / COG;
    constexpr int ROWS  = 2 * TH + 1;
    constexpr int COLS  = 2 * TW + 1;
    constexpr int RS    = 2 * TW + 4;   // even row stride (float2 alignment)
    constexpr int PBLK  = BB * TILES;
    constexpr int NW    = NT / 64;

    __shared__ float lds[CICH * ROWS * RS];
    __shared__ float redbuf[2 * NW * COG];

    int tid = threadIdx.x;
    int bid = blockIdx.x;
    int cg   = bid % COGN;
    int tmp  = bid / COGN;
    int tile = tmp % TILES;
    int b    = tmp / TILES;
    int co0  = cg * COG;
    int ty0  = (tile / TXT) * TH;
    int tx0  = (tile % TXT) * TW;

    int ty = tid / TW, tx = tid % TW;
    int tyc = (ty < TH) ? ty : 0;
    int oy = ty0 + tyc, ox = tx0 + tx;
    bool active = (ty < TH) && (oy < HOUT) && (ox < HOUT);

    float acc[COG];
    #pragma unroll
    for (int i = 0; i < COG; ++i) acc[i] = 0.f;

    const float* inb0 = in + (size_t)b * CIN * HIN * HIN;

    for (int c0 = 0; c0 < CIN; c0 += CICH) {
        __syncthreads();
        const float* inb = inb0 + (size_t)c0 * HIN * HIN;
        for (int t = tid; t < CICH * ROWS * COLS; t += NT) {
            int cl = t / (ROWS * COLS);
            int rem = t % (ROWS * COLS);
            int r = rem / COLS, c = rem % COLS;
            int gy = 2 * ty0 + r, gx = 2 * tx0 + c;
            float v = (gy < HIN && gx < HIN) ? inb[cl * HIN * HIN + gy * HIN + gx] : 0.f;
            if (FUSE) v = fmaxf(fmaf(v, scl[c0 + cl], shf[c0 + cl]), 0.f);
            lds[cl * (ROWS * RS) + r * RS + c] = v;
        }
        __syncthreads();

        #pragma unroll
        for (int cl = 0; cl < CICH; ++cl) {
            const float* lrow = lds + cl * (ROWS * RS) + (2 * tyc) * RS + 2 * tx;
            float p[9];
            #pragma unroll
            for (int ky = 0; ky < 3; ++ky) {
                float2 ab = *(const float2*)(lrow + ky * RS);
                p[ky * 3 + 0] = ab.x;
                p[ky * 3 + 1] = ab.y;
                p[ky * 3 + 2] = lrow[ky * RS + 2];
            }
            int ci = c0 + cl;
            const float* wci = w + ((size_t)co0 * CIN + ci) * 9;
            #pragma unroll
            for (int i = 0; i < COG; ++i) {
                const float* wp = wci + (size_t)i * CIN * 9;  // uniform -> s_load
                float a = acc[i];
                a = fmaf(p[0], wp[0], a);
                a = fmaf(p[1], wp[1], a);
                a = fmaf(p[2], wp[2], a);
                a = fmaf(p[3], wp[3], a);
                a = fmaf(p[4], wp[4], a);
                a = fmaf(p[5], wp[5], a);
                a = fmaf(p[6], wp[6], a);
                a = fmaf(p[7], wp[7], a);
                a = fmaf(p[8], wp[8], a);
                acc[i] = a;
            }
        }
    }

    float* outb = out + ((size_t)b * COUT + co0) * (HOUT * HOUT) + oy * HOUT + ox;
    #pragma unroll
    for (int i = 0; i < COG; ++i) {
        float v = active ? (acc[i] + bias[co0 + i]) : 0.f;
        if (active) outb[(size_t)i * (HOUT * HOUT)] = v;
        acc[i] = v;
    }

    int lane = tid & 63, wv = tid >> 6;
    #pragma unroll
    for (int i = 0; i < COG; ++i) {
        float s = acc[i], q = acc[i] * acc[i];
        #pragma unroll
        for (int o = 32; o > 0; o >>= 1) {
            s += __shfl_down(s, o, 64);
            q += __shfl_down(q, o, 64);
        }
        if (lane == 0) {
            redbuf[wv * COG + i] = s;
            redbuf[NW * COG + wv * COG + i] = q;
        }
    }
    __syncthreads();
    if (tid < COG) {
        float S = 0.f, Q = 0.f;
        #pragma unroll
        for (int v2 = 0; v2 < NW; ++v2) {
            S += redbuf[v2 * COG + tid];
            Q += redbuf[NW * COG + v2 * COG + tid];
        }
        int pb = b * TILES + tile;
        psum[(size_t)(co0 + tid) * PBLK + pb] = S;
        psq [(size_t)(co0 + tid) * PBLK + pb] = Q;
    }
}

// ---------------- conv3: 15->7, CIN=128 split across 4 waves ----------------
// Block = (b, cg of 16 co). 256 threads = 4 waves; wave w owns ci range
// [w*32, w*32+32), stages into its private LDS region (8 ch chunks), computes
// 16 partial accumulators for the 49 pixels (lane = pixel). Cross-wave LDS
// reduce -> bias -> out3 + per-(co,b) stats partials.
__global__ __launch_bounds__(256) void conv3_kernel(
        const float* __restrict__ in,    // [B][128][15][15] raw (pre-BN)
        const float* __restrict__ scl,
        const float* __restrict__ shf,
        const float* __restrict__ w,     // [128][128][3][3]
        const float* __restrict__ bias,
        float* __restrict__ out,         // [B][128][7][7] raw
        float* __restrict__ psum,        // [128][32]
        float* __restrict__ psq) {
    __shared__ float lin[4 * 8 * 270];   // 4 waves x 8 ch x 15 rows x 18 stride
    __shared__ float red[4 * 16 * 49];
    __shared__ float fin[16 * 49];

    int tid = threadIdx.x;
    int wv = tid >> 6, lane = tid & 63;
    int wvu = __builtin_amdgcn_readfirstlane(wv);  // force SGPR for weight addrs
    int b  = blockIdx.x >> 3;
    int cg = blockIdx.x & 7;
    int co0 = cg * 16;
    int oy = lane / 7, ox = lane % 7;
    bool act = lane < 49;

    float acc[16];
    #pragma unroll
    for (int i = 0; i < 16; ++i) acc[i] = 0.f;

    const float* inw = in + (size_t)b * 128 * 225 + (size_t)wvu * 32 * 225;
    float* ldsw = lin + wvu * (8 * 270);

    for (int k = 0; k < 4; ++k) {        // 4 chunks of 8 channels per wave
        __syncthreads();
        const float* src = inw + k * 8 * 225;
        for (int t = lane; t < 8 * 225; t += 64) {
            int cl = t / 225, rem = t % 225;
            int r = rem / 15, c = rem % 15;
            int ci = wvu * 32 + k * 8 + cl;
            float v = fmaxf(fmaf(src[t], scl[ci], shf[ci]), 0.f);
            ldsw[cl * 270 + r * 18 + c] = v;
        }
        __syncthreads();

        #pragma unroll
        for (int cl = 0; cl < 8; ++cl) {
            const float* lrow = ldsw + cl * 270 + (2 * oy) * 18 + 2 * ox;
            float p[9];
            #pragma unroll
            for (int ky = 0; ky < 3; ++ky) {
                float2 ab = *(const float2*)(lrow + ky * 18);
                p[ky * 3 + 0] = ab.x;
                p[ky * 3 + 1] = ab.y;
                p[ky * 3 + 2] = lrow[ky * 18 + 2];
            }
            int ci = wvu * 32 + k * 8 + cl;
            const float* wci = w + ((size_t)co0 * 128 + ci) * 9;
            #pragma unroll
            for (int i = 0; i < 16; ++i) {
                const float* wp = wci + (size_t)i * 128 * 9;  // uniform -> s_load
                float a = acc[i];
                a = fmaf(p[0], wp[0], a);
                a = fmaf(p[1], wp[1], a);
                a = fmaf(p[2], wp[2], a);
                a = fmaf(p[3], wp[3], a);
                a = fmaf(p[4], wp[4], a);
                a = fmaf(p[5], wp[5], a);
                a = fmaf(p[6], wp[6], a);
                a = fmaf(p[7], wp[7], a);
                a = fmaf(p[8], wp[8], a);
                acc[i] = a;
            }
        }
    }

    if (act) {
        #pragma unroll
        for (int i = 0; i < 16; ++i) red[(wv * 16 + i) * 49 + lane] = acc[i];
    }
    __syncthreads();

    for (int t = tid; t < 16 * 49; t += 256) {
        int i = t / 49, p2 = t % 49;
        float v = red[(0 * 16 + i) * 49 + p2] + red[(1 * 16 + i) * 49 + p2] +
                  red[(2 * 16 + i) * 49 + p2] + red[(3 * 16 + i) * 49 + p2];
        v += bias[co0 + i];
        out[((size_t)b * 128 + co0 + i) * 49 + p2] = v;
        fin[t] = v;
    }
    __syncthreads();

    if (tid < 16) {
        float S = 0.f, Q = 0.f;
        for (int p2 = 0; p2 < 49; ++p2) {
            float v = fin[tid * 49 + p2];
            S += v; Q += v * v;
        }
        psum[(size_t)(co0 + tid) * 32 + b] = S;
        psq [(size_t)(co0 + tid) * 32 + b] = Q;
    }
}

// ---------------- Fold partials -> per-channel scale/shift ----------------
__global__ void stats_kernel(const float* __restrict__ psum, const float* __restrict__ psq,
                             const float* __restrict__ g, const float* __restrict__ be,
                             float* __restrict__ scale, float* __restrict__ shift,
                             int COUT, int PBLK, float count) {
    int c = threadIdx.x;
    if (c >= COUT) return;
    float s = 0.f, q = 0.f;
    for (int p = 0; p < PBLK; ++p) {
        s += psum[(size_t)c * PBLK + p];
        q += psq[(size_t)c * PBLK + p];
    }
    float mean = s / count;
    float var  = q / count - mean * mean;
    float sc   = g[c] * rsqrtf(var + 1e-5f);
    scale[c] = sc;
    shift[c] = be[c] - mean * sc;
}

// ---------------- FC1: one block per (b, j) ----------------
__global__ __launch_bounds__(256) void fc1_kernel(
        const float* __restrict__ out3,   // [B][128*49] raw
        const float* __restrict__ scale3, const float* __restrict__ shift3,
        const float* __restrict__ fc1w,   // [64][6272]
        const float* __restrict__ fc1b,
        float* __restrict__ h) {          // [B][64]
    const int FLAT = 128 * 49;
    int b = blockIdx.x >> 6;
    int j = blockIdx.x & 63;
    const float* ip = out3 + (size_t)b * FLAT;
    const float* wp = fc1w + (size_t)j * FLAT;
    float s = 0.f;
    for (int i = threadIdx.x; i < FLAT; i += 256) {
        int c = i / 49;
        float xv = fmaxf(fmaf(ip[i], scale3[c], shift3[c]), 0.f);
        s = fmaf(xv, wp[i], s);
    }
    #pragma unroll
    for (int o = 32; o > 0; o >>= 1) s += __shfl_down(s, o, 64);
    __shared__ float red[4];
    if ((threadIdx.x & 63) == 0) red[threadIdx.x >> 6] = s;
    __syncthreads();
    if (threadIdx.x == 0) {
        float t = red[0] + red[1] + red[2] + red[3];
        h[b * 64 + j] = fmaxf(t + fc1b[j], 0.f);
    }
}

// ---------------- FC2 + sigmoid ----------------
__global__ __launch_bounds__(64) void fc2_kernel(
        const float* __restrict__ h, const float* __restrict__ fc2w,
        const float* __restrict__ fc2b, float* __restrict__ outp) {
    int b = blockIdx.x;
    float v = h[b * 64 + threadIdx.x] * fc2w[threadIdx.x];
    #pragma unroll
    for (int o = 32; o > 0; o >>= 1) v += __shfl_down(v, o, 64);
    if (threadIdx.x == 0) outp[b] = 1.f / (1.f + expf(-(v + fc2b[0])));
}

// ---------------- Launch ----------------
extern "C" void kernel_launch(void* const* d_in, const int* in_sizes, int n_in,
                              void* d_out, int out_size, void* d_ws, size_t ws_size,
                              hipStream_t stream) {
    const float* x       = (const float*)d_in[0];
    const float* conv1_w = (const float*)d_in[1];
    const float* conv1_b = (const float*)d_in[2];
    const float* bn1_g   = (const float*)d_in[3];
    const float* bn1_b   = (const float*)d_in[4];
    const float* conv2_w = (const float*)d_in[5];
    const float* conv2_b = (const float*)d_in[6];
    const float* bn2_g   = (const float*)d_in[7];
    const float* bn2_b   = (const float*)d_in[8];
    const float* conv3_w = (const float*)d_in[9];
    const float* conv3_b = (const float*)d_in[10];
    const float* bn3_g   = (const float*)d_in[11];
    const float* bn3_b   = (const float*)d_in[12];
    const float* fc1_w   = (const float*)d_in[13];
    const float* fc1_b   = (const float*)d_in[14];
    const float* fc2_w   = (const float*)d_in[15];
    const float* fc2_b   = (const float*)d_in[16];
    float* out = (float*)d_out;

    float* ws = (float*)d_ws;
    size_t off = 0;
    float* layout = ws + off; off += (size_t)BB * NREC * HW * HW;
    float* out1   = ws + off; off += (size_t)BB * 64  * 31 * 31;
    float* out2   = ws + off; off += (size_t)BB * 128 * 15 * 15;
    float* out3   = ws + off; off += (size_t)BB * 128 * 7 * 7;
    float* psum1  = ws + off; off += 64 * 128;   // conv1: PBLK = 32*4
    float* psq1   = ws + off; off += 64 * 128;
    float* psum2  = ws + off; off += 128 * 32;
    float* psq2   = ws + off; off += 128 * 32;
    float* psum3  = ws + off; off += 128 * 32;
    float* psq3   = ws + off; off += 128 * 32;
    float* scale1 = ws + off; off += 64;
    float* shift1 = ws + off; off += 64;
    float* scale2 = ws + off; off += 128;
    float* shift2 = ws + off; off += 128;
    float* scale3 = ws + off; off += 128;
    float* shift3 = ws + off; off += 128;
    float* hbuf   = ws + off; off += BB * 64;

    render_kernel<<<BB * NREC, 256, 0, stream>>>(x, layout);

    // conv1: 63->31, 2x2 tiles of 16x16, COG=8 -> grid 32*4*8 = 1024
    conv_kernel<64, 64, 63, 31, 16, 16, 256, 8, 4, false>
        <<<32 * 4 * 8, 256, 0, stream>>>(layout, nullptr, nullptr,
                                         conv1_w, conv1_b, out1, psum1, psq1);
    stats_kernel<<<1, 64, 0, stream>>>(psum1, psq1, bn1_g, bn1_b, scale1, shift1,
                                       64, 32 * 4, (float)(BB * 31 * 31));

    // conv2: 31->15, single 15x15 tile, COG=4 -> grid 32*32 = 1024
    conv_kernel<64, 128, 31, 15, 15, 15, 256, 4, 4, true>
        <<<32 * 32, 256, 0, stream>>>(out1, scale1, shift1,
                                      conv2_w, conv2_b, out2, psum2, psq2);
    stats_kernel<<<1, 128, 0, stream>>>(psum2, psq2, bn2_g, bn2_b, scale2, shift2,
                                        128, 32, (float)(BB * 15 * 15));

    // conv3: 15->7, wave-split CIN, 16 co per block -> grid 32*8 = 256
    conv3_kernel<<<32 * 8, 256, 0, stream>>>(out2, scale2, shift2,
                                             conv3_w, conv3_b, out3, psum3, psq3);
    stats_kernel<<<1, 128, 0, stream>>>(psum3, psq3, bn3_g, bn3_b, scale3, shift3,
                                        128, 32, (float)(BB * 7 * 7));

    fc1_kernel<<<BB * 64, 256, 0, stream>>>(out3, scale3, shift3, fc1_w, fc1_b, hbuf);
    fc2_kernel<<<BB, 64, 0, stream>>>(hbuf, fc2_w, fc2_b, out);
}

// Round 5
// 224.939 us; speedup vs baseline: 2.9388x; 1.6301x over previous
//
#include <hip/hip_runtime.h>
#include <math.h>

// Problem constants
#define BB 32
#define NREC 64
#define CC 16
#define HW 63

// ---------------- Rectangle render ----------------
__global__ __launch_bounds__(256) void render_kernel(const float* __restrict__ x,
                                                     float* __restrict__ layout) {
    int bn = blockIdx.x;                 // b*NREC + n
    const float* xp = x + (size_t)bn * (4 + CC);
    __shared__ int cs[4];
    __shared__ float mps;
    if (threadIdx.x == 0) {
        cs[0] = (int)xp[0]; cs[1] = (int)xp[1];
        cs[2] = (int)xp[2]; cs[3] = (int)xp[3];
        float m = xp[4];
        #pragma unroll
        for (int c = 1; c < CC; ++c) m = fmaxf(m, xp[4 + c]);
        mps = m;
    }
    __syncthreads();
    int xL = cs[0], yT = cs[1], xR = cs[2], yB = cs[3];
    float m = mps;
    float* op = layout + (size_t)bn * HW * HW;
    for (int p = threadIdx.x; p < HW * HW; p += blockDim.x) {
        int u = p / HW, v = p % HW;
        bool vb = ((u == xL || u == xR) && (v > yT && v < yB)) ||
                  ((v == yT || v == yB) && (u > xL && u < xR));
        op[p] = vb ? m : 0.0f;
    }
}

// ---------------- Conv 3x3 stride-2 VALID (conv1/conv2) ----------------
// Block = (cg MAJOR for XCD-L2 sharing, b, tile). Thread = one output pixel,
// COG independent accumulators. Staging slots precomputed once (same (r,c)
// for every channel); register prefetch double-buffers global->LDS staging.
template<int CIN, int COUT, int HIN, int HOUT, int TH, int TW, int NT,
         int COG, int CICH, bool FUSE>
__global__ __launch_bounds__(NT) void conv_kernel(
        const float* __restrict__ in,
        const float* __restrict__ scl,
        const float* __restrict__ shf,
        const float* __restrict__ w,     // [COUT][CIN][3][3]
        const float* __restrict__ bias,
        float* __restrict__ out,         // raw (pre-BN)
        float* __restrict__ psum,        // [COUT][PBLK]
        float* __restrict__ psq) {
    constexpr int TYT   = (HOUT + TH - 1) / TH;
    constexpr int TXT   = (HOUT + TW - 1) / TW;
    constexpr int TILES = TYT * TXT;
    constexpr int ROWS  = 2 * TH + 1;
    constexpr int COLS  = 2 * TW + 1;
    constexpr int RS    = 2 * TW + 4;   // even row stride (float2 alignment)
    constexpr int PBLK  = BB * TILES;
    constexpr int NW    = NT / 64;
    constexpr int AREA  = ROWS * COLS;
    constexpr int S     = (AREA + NT - 1) / NT;   // staging slots per channel

    __shared__ float lds[CICH * ROWS * RS];
    __shared__ float redbuf[2 * NW * COG];

    int tid = threadIdx.x;
    int bid = blockIdx.x;
    int cg   = bid / PBLK;              // cg-major: same-tile blocks -> same XCD
    int tmp  = bid % PBLK;
    int tile = tmp % TILES;
    int b    = tmp / TILES;
    int co0  = cg * COG;
    int ty0  = (tile / TXT) * TH;
    int tx0  = (tile % TXT) * TW;

    int ty = tid / TW, tx = tid % TW;
    int tyc = (ty < TH) ? ty : 0;
    int oy = ty0 + tyc, ox = tx0 + tx;
    bool active = (ty < TH) && (oy < HOUT) && (ox < HOUT);

    // Precompute staging slots once (identical for every channel)
    int soffw[S], loffw[S];
    #pragma unroll
    for (int s = 0; s < S; ++s) {
        int t = tid + s * NT;
        if (t < AREA) {
            int r = t / COLS, c = t % COLS;
            int gy = 2 * ty0 + r, gx = 2 * tx0 + c;
            bool ok = (gy < HIN) && (gx < HIN);
            soffw[s] = ok ? (gy * HIN + gx) : -1;
            loffw[s] = r * RS + c;
        } else { soffw[s] = -1; loffw[s] = -1; }
    }

    float acc[COG];
    #pragma unroll
    for (int i = 0; i < COG; ++i) acc[i] = 0.f;

    const float* inb0 = in + (size_t)b * CIN * HIN * HIN;

    // register prefetch buffer (statically indexed)
    float pf[CICH][S];
    #pragma unroll
    for (int cl = 0; cl < CICH; ++cl) {
        const float* cp = inb0 + (size_t)cl * (HIN * HIN);
        #pragma unroll
        for (int s = 0; s < S; ++s)
            pf[cl][s] = (soffw[s] >= 0) ? cp[soffw[s]] : 0.f;
    }

    for (int c0 = 0; c0 < CIN; c0 += CICH) {
        __syncthreads();   // prior compute done reading LDS
        // write prefetched chunk (BN+ReLU of previous layer fused here)
        #pragma unroll
        for (int cl = 0; cl < CICH; ++cl) {
            float s_ = FUSE ? scl[c0 + cl] : 0.f;
            float h_ = FUSE ? shf[c0 + cl] : 0.f;
            #pragma unroll
            for (int s = 0; s < S; ++s) {
                if (loffw[s] >= 0) {
                    float v = pf[cl][s];
                    if (FUSE) v = fmaxf(fmaf(v, s_, h_), 0.f);
                    lds[cl * (ROWS * RS) + loffw[s]] = v;
                }
            }
        }
        __syncthreads();
        // issue next chunk's loads now; latency hides under the FMAs below
        if (c0 + CICH < CIN) {
            const float* nb = inb0 + (size_t)(c0 + CICH) * (HIN * HIN);
            #pragma unroll
            for (int cl = 0; cl < CICH; ++cl) {
                const float* cp = nb + (size_t)cl * (HIN * HIN);
                #pragma unroll
                for (int s = 0; s < S; ++s)
                    pf[cl][s] = (soffw[s] >= 0) ? cp[soffw[s]] : 0.f;
            }
        }
        // compute current chunk
        #pragma unroll
        for (int cl = 0; cl < CICH; ++cl) {
            const float* lrow = lds + cl * (ROWS * RS) + (2 * tyc) * RS + 2 * tx;
            float p[9];
            #pragma unroll
            for (int ky = 0; ky < 3; ++ky) {
                float2 ab = *(const float2*)(lrow + ky * RS);
                p[ky * 3 + 0] = ab.x;
                p[ky * 3 + 1] = ab.y;
                p[ky * 3 + 2] = lrow[ky * RS + 2];
            }
            const float* wci = w + ((size_t)co0 * CIN + (c0 + cl)) * 9;
            #pragma unroll
            for (int i = 0; i < COG; ++i) {
                const float* wp = wci + (size_t)i * CIN * 9;  // uniform -> s_load
                float a = acc[i];
                a = fmaf(p[0], wp[0], a);
                a = fmaf(p[1], wp[1], a);
                a = fmaf(p[2], wp[2], a);
                a = fmaf(p[3], wp[3], a);
                a = fmaf(p[4], wp[4], a);
                a = fmaf(p[5], wp[5], a);
                a = fmaf(p[6], wp[6], a);
                a = fmaf(p[7], wp[7], a);
                a = fmaf(p[8], wp[8], a);
                acc[i] = a;
            }
        }
    }

    float* outb = out + ((size_t)b * COUT + co0) * (HOUT * HOUT) + oy * HOUT + ox;
    #pragma unroll
    for (int i = 0; i < COG; ++i) {
        float v = active ? (acc[i] + bias[co0 + i]) : 0.f;
        if (active) outb[(size_t)i * (HOUT * HOUT)] = v;
        acc[i] = v;
    }

    int lane = tid & 63, wv = tid >> 6;
    #pragma unroll
    for (int i = 0; i < COG; ++i) {
        float s = acc[i], q = acc[i] * acc[i];
        #pragma unroll
        for (int o = 32; o > 0; o >>= 1) {
            s += __shfl_down(s, o, 64);
            q += __shfl_down(q, o, 64);
        }
        if (lane == 0) {
            redbuf[wv * COG + i] = s;
            redbuf[NW * COG + wv * COG + i] = q;
        }
    }
    __syncthreads();
    if (tid < COG) {
        float S_ = 0.f, Q_ = 0.f;
        #pragma unroll
        for (int v2 = 0; v2 < NW; ++v2) {
            S_ += redbuf[v2 * COG + tid];
            Q_ += redbuf[NW * COG + v2 * COG + tid];
        }
        int pb = b * TILES + tile;
        psum[(size_t)(co0 + tid) * PBLK + pb] = S_;
        psq [(size_t)(co0 + tid) * PBLK + pb] = Q_;
    }
}

// ---------------- conv3: 15->7, CIN=128 split across 4 waves, COG=8 --------
__global__ __launch_bounds__(256) void conv3_kernel(
        const float* __restrict__ in,    // [B][128][15][15] raw (pre-BN)
        const float* __restrict__ scl,
        const float* __restrict__ shf,
        const float* __restrict__ w,     // [128][128][3][3]
        const float* __restrict__ bias,
        float* __restrict__ out,         // [B][128][7][7] raw
        float* __restrict__ psum,        // [128][32]
        float* __restrict__ psq) {
    constexpr int COG = 8;
    __shared__ float lin[4 * 8 * 270];   // 4 waves x 8 ch x (15 rows x 18)
    __shared__ float red[4 * COG * 49];
    __shared__ float fin[COG * 49];

    int tid = threadIdx.x;
    int wv = tid >> 6, lane = tid & 63;
    int wvu = __builtin_amdgcn_readfirstlane(wv);
    int cg = blockIdx.x >> 5;            // cg-major: same-b blocks share XCD L2
    int b  = blockIdx.x & 31;
    int co0 = cg * COG;
    int oy = lane / 7, ox = lane % 7;
    bool act = lane < 49;

    // staging slots: area 225, contiguous source
    int loffw[4];
    #pragma unroll
    for (int s = 0; s < 4; ++s) {
        int t = lane + s * 64;
        if (t < 225) {
            int r = t / 15, c = t % 15;
            loffw[s] = r * 18 + c;
        } else loffw[s] = -1;
    }

    float acc[COG];
    #pragma unroll
    for (int i = 0; i < COG; ++i) acc[i] = 0.f;

    const float* inw = in + (size_t)b * 128 * 225 + (size_t)wvu * 32 * 225;
    float* ldsw = lin + wvu * (8 * 270);

    float pf[8][4];
    #pragma unroll
    for (int cl = 0; cl < 8; ++cl) {
        #pragma unroll
        for (int s = 0; s < 4; ++s) {
            int t = lane + s * 64;
            pf[cl][s] = (t < 225) ? inw[cl * 225 + t] : 0.f;
        }
    }

    for (int kk = 0; kk < 4; ++kk) {     // 4 chunks of 8 channels per wave
        __syncthreads();
        #pragma unroll
        for (int cl = 0; cl < 8; ++cl) {
            int ci = wvu * 32 + kk * 8 + cl;
            float s_ = scl[ci], h_ = shf[ci];
            #pragma unroll
            for (int s = 0; s < 4; ++s)
                if (loffw[s] >= 0)
                    ldsw[cl * 270 + loffw[s]] = fmaxf(fmaf(pf[cl][s], s_, h_), 0.f);
        }
        __syncthreads();
        if (kk < 3) {
            const float* nb = inw + (size_t)(kk + 1) * 8 * 225;
            #pragma unroll
            for (int cl = 0; cl < 8; ++cl) {
                #pragma unroll
                for (int s = 0; s < 4; ++s) {
                    int t = lane + s * 64;
                    pf[cl][s] = (t < 225) ? nb[cl * 225 + t] : 0.f;
                }
            }
        }
        #pragma unroll
        for (int cl = 0; cl < 8; ++cl) {
            const float* lrow = ldsw + cl * 270 + (2 * oy) * 18 + 2 * ox;
            float p[9];
            #pragma unroll
            for (int ky = 0; ky < 3; ++ky) {
                float2 ab = *(const float2*)(lrow + ky * 18);
                p[ky * 3 + 0] = ab.x;
                p[ky * 3 + 1] = ab.y;
                p[ky * 3 + 2] = lrow[ky * 18 + 2];
            }
            int ci = wvu * 32 + kk * 8 + cl;
            const float* wci = w + ((size_t)co0 * 128 + ci) * 9;
            #pragma unroll
            for (int i = 0; i < COG; ++i) {
                const float* wp = wci + (size_t)i * 128 * 9;  // uniform -> s_load
                float a = acc[i];
                a = fmaf(p[0], wp[0], a);
                a = fmaf(p[1], wp[1], a);
                a = fmaf(p[2], wp[2], a);
                a = fmaf(p[3], wp[3], a);
                a = fmaf(p[4], wp[4], a);
                a = fmaf(p[5], wp[5], a);
                a = fmaf(p[6], wp[6], a);
                a = fmaf(p[7], wp[7], a);
                a = fmaf(p[8], wp[8], a);
                acc[i] = a;
            }
        }
    }

    if (act) {
        #pragma unroll
        for (int i = 0; i < COG; ++i) red[(wv * COG + i) * 49 + lane] = acc[i];
    }
    __syncthreads();

    for (int t = tid; t < COG * 49; t += 256) {
        int i = t / 49, p2 = t % 49;
        float v = red[(0 * COG + i) * 49 + p2] + red[(1 * COG + i) * 49 + p2] +
                  red[(2 * COG + i) * 49 + p2] + red[(3 * COG + i) * 49 + p2];
        v += bias[co0 + i];
        out[((size_t)b * 128 + co0 + i) * 49 + p2] = v;
        fin[t] = v;
    }
    __syncthreads();

    if (tid < COG) {
        float S = 0.f, Q = 0.f;
        for (int p2 = 0; p2 < 49; ++p2) {
            float v = fin[tid * 49 + p2];
            S += v; Q += v * v;
        }
        psum[(size_t)(co0 + tid) * 32 + b] = S;
        psq [(size_t)(co0 + tid) * 32 + b] = Q;
    }
}

// ---------------- Fold partials -> per-channel scale/shift ----------------
__global__ void stats_kernel(const float* __restrict__ psum, const float* __restrict__ psq,
                             const float* __restrict__ g, const float* __restrict__ be,
                             float* __restrict__ scale, float* __restrict__ shift,
                             int COUT, int PBLK, float count) {
    int c = threadIdx.x;
    if (c >= COUT) return;
    float s = 0.f, q = 0.f;
    for (int p = 0; p < PBLK; ++p) {
        s += psum[(size_t)c * PBLK + p];
        q += psq[(size_t)c * PBLK + p];
    }
    float mean = s / count;
    float var  = q / count - mean * mean;
    float sc   = g[c] * rsqrtf(var + 1e-5f);
    scale[c] = sc;
    shift[c] = be[c] - mean * sc;
}

// ---------------- FC1: one block per (j, b), j-major ----------------
__global__ __launch_bounds__(256) void fc1_kernel(
        const float* __restrict__ out3,   // [B][128*49] raw
        const float* __restrict__ scale3, const float* __restrict__ shift3,
        const float* __restrict__ fc1w,   // [64][6272]
        const float* __restrict__ fc1b,
        float* __restrict__ h) {          // [B][64]
    const int FLAT = 128 * 49;
    int j = blockIdx.x >> 5;
    int b = blockIdx.x & 31;
    const float* ip = out3 + (size_t)b * FLAT;
    const float* wp = fc1w + (size_t)j * FLAT;
    float s = 0.f;
    for (int i = threadIdx.x; i < FLAT; i += 256) {
        int c = i / 49;
        float xv = fmaxf(fmaf(ip[i], scale3[c], shift3[c]), 0.f);
        s = fmaf(xv, wp[i], s);
    }
    #pragma unroll
    for (int o = 32; o > 0; o >>= 1) s += __shfl_down(s, o, 64);
    __shared__ float red[4];
    if ((threadIdx.x & 63) == 0) red[threadIdx.x >> 6] = s;
    __syncthreads();
    if (threadIdx.x == 0) {
        float t = red[0] + red[1] + red[2] + red[3];
        h[b * 64 + j] = fmaxf(t + fc1b[j], 0.f);
    }
}

// ---------------- FC2 + sigmoid ----------------
__global__ __launch_bounds__(64) void fc2_kernel(
        const float* __restrict__ h, const float* __restrict__ fc2w,
        const float* __restrict__ fc2b, float* __restrict__ outp) {
    int b = blockIdx.x;
    float v = h[b * 64 + threadIdx.x] * fc2w[threadIdx.x];
    #pragma unroll
    for (int o = 32; o > 0; o >>= 1) v += __shfl_down(v, o, 64);
    if (threadIdx.x == 0) outp[b] = 1.f / (1.f + expf(-(v + fc2b[0])));
}

// ---------------- Launch ----------------
extern "C" void kernel_launch(void* const* d_in, const int* in_sizes, int n_in,
                              void* d_out, int out_size, void* d_ws, size_t ws_size,
                              hipStream_t stream) {
    const float* x       = (const float*)d_in[0];
    const float* conv1_w = (const float*)d_in[1];
    const float* conv1_b = (const float*)d_in[2];
    const float* bn1_g   = (const float*)d_in[3];
    const float* bn1_b   = (const float*)d_in[4];
    const float* conv2_w = (const float*)d_in[5];
    const float* conv2_b = (const float*)d_in[6];
    const float* bn2_g   = (const float*)d_in[7];
    const float* bn2_b   = (const float*)d_in[8];
    const float* conv3_w = (const float*)d_in[9];
    const float* conv3_b = (const float*)d_in[10];
    const float* bn3_g   = (const float*)d_in[11];
    const float* bn3_b   = (const float*)d_in[12];
    const float* fc1_w   = (const float*)d_in[13];
    const float* fc1_b   = (const float*)d_in[14];
    const float* fc2_w   = (const float*)d_in[15];
    const float* fc2_b   = (const float*)d_in[16];
    float* out = (float*)d_out;

    float* ws = (float*)d_ws;
    size_t off = 0;
    float* layout = ws + off; off += (size_t)BB * NREC * HW * HW;
    float* out1   = ws + off; off += (size_t)BB * 64  * 31 * 31;
    float* out2   = ws + off; off += (size_t)BB * 128 * 15 * 15;
    float* out3   = ws + off; off += (size_t)BB * 128 * 7 * 7;
    float* psum1  = ws + off; off += 64 * 128;
    float* psq1   = ws + off; off += 64 * 128;
    float* psum2  = ws + off; off += 128 * 32;
    float* psq2   = ws + off; off += 128 * 32;
    float* psum3  = ws + off; off += 128 * 32;
    float* psq3   = ws + off; off += 128 * 32;
    float* scale1 = ws + off; off += 64;
    float* shift1 = ws + off; off += 64;
    float* scale2 = ws + off; off += 128;
    float* shift2 = ws + off; off += 128;
    float* scale3 = ws + off; off += 128;
    float* shift3 = ws + off; off += 128;
    float* hbuf   = ws + off; off += BB * 64;

    render_kernel<<<BB * NREC, 256, 0, stream>>>(x, layout);

    // conv1: 63->31, 2x2 tiles of 16x16, COG=8, cg-major -> grid 8*128 = 1024
    conv_kernel<64, 64, 63, 31, 16, 16, 256, 8, 4, false>
        <<<8 * 32 * 4, 256, 0, stream>>>(layout, nullptr, nullptr,
                                         conv1_w, conv1_b, out1, psum1, psq1);
    stats_kernel<<<1, 64, 0, stream>>>(psum1, psq1, bn1_g, bn1_b, scale1, shift1,
                                       64, 32 * 4, (float)(BB * 31 * 31));

    // conv2: 31->15, single tile, COG=4, cg-major -> grid 32*32 = 1024
    conv_kernel<64, 128, 31, 15, 15, 15, 256, 4, 4, true>
        <<<32 * 32, 256, 0, stream>>>(out1, scale1, shift1,
                                      conv2_w, conv2_b, out2, psum2, psq2);
    stats_kernel<<<1, 128, 0, stream>>>(psum2, psq2, bn2_g, bn2_b, scale2, shift2,
                                        128, 32, (float)(BB * 15 * 15));

    // conv3: 15->7, wave-split CIN, COG=8, cg-major -> grid 16*32 = 512
    conv3_kernel<<<16 * 32, 256, 0, stream>>>(out2, scale2, shift2,
                                              conv3_w, conv3_b, out3, psum3, psq3);
    stats_kernel<<<1, 128, 0, stream>>>(psum3, psq3, bn3_g, bn3_b, scale3, shift3,
                                        128, 32, (float)(BB * 7 * 7));

    fc1_kernel<<<64 * 32, 256, 0, stream>>>(out3, scale3, shift3, fc1_w, fc1_b, hbuf);
    fc2_kernel<<<BB, 64, 0, stream>>>(hbuf, fc2_w, fc2_b, out);
}

// Round 6
// 197.877 us; speedup vs baseline: 3.3407x; 1.1368x over previous
//
#include <hip/hip_runtime.h>
#include <math.h>

// Problem constants
#define BB 32
#define NREC 64
#define CC 16
#define HW 63

// ---------------- Rectangle render ----------------
__global__ __launch_bounds__(256) void render_kernel(const float* __restrict__ x,
                                                     float* __restrict__ layout) {
    int bn = blockIdx.x;                 // b*NREC + n
    const float* xp = x + (size_t)bn * (4 + CC);
    __shared__ int cs[4];
    __shared__ float mps;
    if (threadIdx.x == 0) {
        cs[0] = (int)xp[0]; cs[1] = (int)xp[1];
        cs[2] = (int)xp[2]; cs[3] = (int)xp[3];
        float m = xp[4];
        #pragma unroll
        for (int c = 1; c < CC; ++c) m = fmaxf(m, xp[4 + c]);
        mps = m;
    }
    __syncthreads();
    int xL = cs[0], yT = cs[1], xR = cs[2], yB = cs[3];
    float m = mps;
    float* op = layout + (size_t)bn * HW * HW;
    for (int p = threadIdx.x; p < HW * HW; p += blockDim.x) {
        int u = p / HW, v = p % HW;
        bool vb = ((u == xL || u == xR) && (v > yT && v < yB)) ||
                  ((v == yT || v == yB) && (u > xL && u < xR));
        op[p] = vb ? m : 0.0f;
    }
}

// ---------------- Conv 3x3 stride-2 VALID, register-direct ----------------
// No LDS in the main loop: each thread keeps its 9-float patch in registers
// (2-deep double buffer, named pa/pb), weights via block-uniform s_load.
// Input must be pre-activated (BN+ReLU applied by apply_kernel).
template<int CIN, int COUT, int HIN, int HOUT, int TH, int TW, int NT, int COG>
__global__ __launch_bounds__(NT) void convd_kernel(
        const float* __restrict__ in,    // [B][CIN][HIN][HIN] activated
        const float* __restrict__ w,     // [COUT][CIN][3][3]
        const float* __restrict__ bias,
        float* __restrict__ out,         // raw (pre-BN)
        float* __restrict__ psum,        // [COUT][PBLK]
        float* __restrict__ psq) {
    constexpr int TYT   = (HOUT + TH - 1) / TH;
    constexpr int TXT   = (HOUT + TW - 1) / TW;
    constexpr int TILES = TYT * TXT;
    constexpr int PBLK  = BB * TILES;
    constexpr int NW    = NT / 64;

    __shared__ float redbuf[2 * NW * COG];

    int tid = threadIdx.x;
    int bid = blockIdx.x;
    int cg   = bid / PBLK;              // cg-major: same-input blocks same XCD
    int tmp  = bid % PBLK;
    int tile = tmp % TILES;
    int b    = tmp / TILES;
    int co0  = cg * COG;
    int ty0  = (tile / TXT) * TH;
    int tx0  = (tile % TXT) * TW;

    int ty = tid / TW, tx = tid % TW;
    int tyc = (ty < TH) ? ty : 0;
    int oy = ty0 + tyc, ox = tx0 + tx;
    bool active = (ty < TH) && (oy < HOUT) && (ox < HOUT);
    int iy = active ? 2 * oy : 0;
    int ix = active ? 2 * ox : 0;
    const float* base = in + (size_t)b * CIN * HIN * HIN + (size_t)iy * HIN + ix;
    const size_t PL = (size_t)HIN * HIN;

    float acc[COG];
    #pragma unroll
    for (int i = 0; i < COG; ++i) acc[i] = 0.f;

    float pa[9], pb[9];
    #pragma unroll
    for (int r = 0; r < 3; ++r) {
        pa[r * 3 + 0] = base[r * HIN + 0];
        pa[r * 3 + 1] = base[r * HIN + 1];
        pa[r * 3 + 2] = base[r * HIN + 2];
    }

    for (int ci = 0; ci < CIN; ci += 2) {
        // prefetch odd channel while even computes
        const float* nb = base + (size_t)(ci + 1) * PL;
        #pragma unroll
        for (int r = 0; r < 3; ++r) {
            pb[r * 3 + 0] = nb[r * HIN + 0];
            pb[r * 3 + 1] = nb[r * HIN + 1];
            pb[r * 3 + 2] = nb[r * HIN + 2];
        }
        {
            const float* wci = w + ((size_t)co0 * CIN + ci) * 9;
            #pragma unroll
            for (int i = 0; i < COG; ++i) {
                const float* wp = wci + (size_t)i * CIN * 9;  // uniform -> s_load
                float a = acc[i];
                a = fmaf(pa[0], wp[0], a); a = fmaf(pa[1], wp[1], a);
                a = fmaf(pa[2], wp[2], a); a = fmaf(pa[3], wp[3], a);
                a = fmaf(pa[4], wp[4], a); a = fmaf(pa[5], wp[5], a);
                a = fmaf(pa[6], wp[6], a); a = fmaf(pa[7], wp[7], a);
                a = fmaf(pa[8], wp[8], a);
                acc[i] = a;
            }
        }
        if (ci + 2 < CIN) {
            const float* nb2 = base + (size_t)(ci + 2) * PL;
            #pragma unroll
            for (int r = 0; r < 3; ++r) {
                pa[r * 3 + 0] = nb2[r * HIN + 0];
                pa[r * 3 + 1] = nb2[r * HIN + 1];
                pa[r * 3 + 2] = nb2[r * HIN + 2];
            }
        }
        {
            const float* wci = w + ((size_t)co0 * CIN + (ci + 1)) * 9;
            #pragma unroll
            for (int i = 0; i < COG; ++i) {
                const float* wp = wci + (size_t)i * CIN * 9;
                float a = acc[i];
                a = fmaf(pb[0], wp[0], a); a = fmaf(pb[1], wp[1], a);
                a = fmaf(pb[2], wp[2], a); a = fmaf(pb[3], wp[3], a);
                a = fmaf(pb[4], wp[4], a); a = fmaf(pb[5], wp[5], a);
                a = fmaf(pb[6], wp[6], a); a = fmaf(pb[7], wp[7], a);
                a = fmaf(pb[8], wp[8], a);
                acc[i] = a;
            }
        }
    }

    float* outb = out + ((size_t)b * COUT + co0) * (HOUT * HOUT) + oy * HOUT + ox;
    #pragma unroll
    for (int i = 0; i < COG; ++i) {
        float v = active ? (acc[i] + bias[co0 + i]) : 0.f;
        if (active) outb[(size_t)i * (HOUT * HOUT)] = v;
        acc[i] = v;
    }

    int lane = tid & 63, wv = tid >> 6;
    #pragma unroll
    for (int i = 0; i < COG; ++i) {
        float s = acc[i], q = acc[i] * acc[i];
        #pragma unroll
        for (int o = 32; o > 0; o >>= 1) {
            s += __shfl_down(s, o, 64);
            q += __shfl_down(q, o, 64);
        }
        if (lane == 0) {
            redbuf[wv * COG + i] = s;
            redbuf[NW * COG + wv * COG + i] = q;
        }
    }
    __syncthreads();
    if (tid < COG) {
        float S_ = 0.f, Q_ = 0.f;
        #pragma unroll
        for (int v2 = 0; v2 < NW; ++v2) {
            S_ += redbuf[v2 * COG + tid];
            Q_ += redbuf[NW * COG + v2 * COG + tid];
        }
        int pb_ = b * TILES + tile;
        psum[(size_t)(co0 + tid) * PBLK + pb_] = S_;
        psq [(size_t)(co0 + tid) * PBLK + pb_] = Q_;
    }
}

// ---------------- conv3: 15->7, CIN=128 split across 4 waves, COG=8 --------
__global__ __launch_bounds__(256) void conv3_kernel(
        const float* __restrict__ in,    // [B][128][15][15] ACTIVATED
        const float* __restrict__ w,     // [128][128][3][3]
        const float* __restrict__ bias,
        float* __restrict__ out,         // [B][128][7][7] raw
        float* __restrict__ psum,        // [128][32]
        float* __restrict__ psq) {
    constexpr int COG = 8;
    __shared__ float lin[4 * 8 * 270];   // 4 waves x 8 ch x (15 rows x 18)
    __shared__ float red[4 * COG * 49];
    __shared__ float fin[COG * 49];

    int tid = threadIdx.x;
    int wv = tid >> 6, lane = tid & 63;
    int wvu = __builtin_amdgcn_readfirstlane(wv);
    int cg = blockIdx.x >> 5;            // cg-major
    int b  = blockIdx.x & 31;
    int co0 = cg * COG;
    int oy = lane / 7, ox = lane % 7;
    bool act = lane < 49;

    int loffw[4];
    #pragma unroll
    for (int s = 0; s < 4; ++s) {
        int t = lane + s * 64;
        if (t < 225) {
            int r = t / 15, c = t % 15;
            loffw[s] = r * 18 + c;
        } else loffw[s] = -1;
    }

    float acc[COG];
    #pragma unroll
    for (int i = 0; i < COG; ++i) acc[i] = 0.f;

    const float* inw = in + (size_t)b * 128 * 225 + (size_t)wvu * 32 * 225;
    float* ldsw = lin + wvu * (8 * 270);

    float pf[8][4];
    #pragma unroll
    for (int cl = 0; cl < 8; ++cl) {
        #pragma unroll
        for (int s = 0; s < 4; ++s) {
            int t = lane + s * 64;
            pf[cl][s] = (t < 225) ? inw[cl * 225 + t] : 0.f;
        }
    }

    for (int kk = 0; kk < 4; ++kk) {
        __syncthreads();
        #pragma unroll
        for (int cl = 0; cl < 8; ++cl) {
            #pragma unroll
            for (int s = 0; s < 4; ++s)
                if (loffw[s] >= 0)
                    ldsw[cl * 270 + loffw[s]] = pf[cl][s];
        }
        __syncthreads();
        if (kk < 3) {
            const float* nb = inw + (size_t)(kk + 1) * 8 * 225;
            #pragma unroll
            for (int cl = 0; cl < 8; ++cl) {
                #pragma unroll
                for (int s = 0; s < 4; ++s) {
                    int t = lane + s * 64;
                    pf[cl][s] = (t < 225) ? nb[cl * 225 + t] : 0.f;
                }
            }
        }
        #pragma unroll
        for (int cl = 0; cl < 8; ++cl) {
            const float* lrow = ldsw + cl * 270 + (2 * oy) * 18 + 2 * ox;
            float p[9];
            #pragma unroll
            for (int ky = 0; ky < 3; ++ky) {
                float2 ab = *(const float2*)(lrow + ky * 18);
                p[ky * 3 + 0] = ab.x;
                p[ky * 3 + 1] = ab.y;
                p[ky * 3 + 2] = lrow[ky * 18 + 2];
            }
            int ci = wvu * 32 + kk * 8 + cl;
            const float* wci = w + ((size_t)co0 * 128 + ci) * 9;
            #pragma unroll
            for (int i = 0; i < COG; ++i) {
                const float* wp = wci + (size_t)i * 128 * 9;
                float a = acc[i];
                a = fmaf(p[0], wp[0], a); a = fmaf(p[1], wp[1], a);
                a = fmaf(p[2], wp[2], a); a = fmaf(p[3], wp[3], a);
                a = fmaf(p[4], wp[4], a); a = fmaf(p[5], wp[5], a);
                a = fmaf(p[6], wp[6], a); a = fmaf(p[7], wp[7], a);
                a = fmaf(p[8], wp[8], a);
                acc[i] = a;
            }
        }
    }

    if (act) {
        #pragma unroll
        for (int i = 0; i < COG; ++i) red[(wv * COG + i) * 49 + lane] = acc[i];
    }
    __syncthreads();

    for (int t = tid; t < COG * 49; t += 256) {
        int i = t / 49, p2 = t % 49;
        float v = red[(0 * COG + i) * 49 + p2] + red[(1 * COG + i) * 49 + p2] +
                  red[(2 * COG + i) * 49 + p2] + red[(3 * COG + i) * 49 + p2];
        v += bias[co0 + i];
        out[((size_t)b * 128 + co0 + i) * 49 + p2] = v;
        fin[t] = v;
    }
    __syncthreads();

    if (tid < COG) {
        float S = 0.f, Q = 0.f;
        for (int p2 = 0; p2 < 49; ++p2) {
            float v = fin[tid * 49 + p2];
            S += v; Q += v * v;
        }
        psum[(size_t)(co0 + tid) * 32 + b] = S;
        psq [(size_t)(co0 + tid) * 32 + b] = Q;
    }
}

// ---------------- Fold partials -> per-channel scale/shift ----------------
__global__ void stats_kernel(const float* __restrict__ psum, const float* __restrict__ psq,
                             const float* __restrict__ g, const float* __restrict__ be,
                             float* __restrict__ scale, float* __restrict__ shift,
                             int COUT, int PBLK, float count) {
    int c = threadIdx.x;
    if (c >= COUT) return;
    float s = 0.f, q = 0.f;
    for (int p = 0; p < PBLK; ++p) {
        s += psum[(size_t)c * PBLK + p];
        q += psq[(size_t)c * PBLK + p];
    }
    float mean = s / count;
    float var  = q / count - mean * mean;
    float sc   = g[c] * rsqrtf(var + 1e-5f);
    scale[c] = sc;
    shift[c] = be[c] - mean * sc;
}

// ---------------- Apply BN+ReLU: one block per (b,c) plane ----------------
__global__ __launch_bounds__(256) void apply_kernel(
        const float* __restrict__ raw, const float* __restrict__ scale,
        const float* __restrict__ shift, float* __restrict__ act,
        int C, int HW2) {
    int bc = blockIdx.x;
    int c = bc % C;
    const float* rp = raw + (size_t)bc * HW2;
    float* ap = act + (size_t)bc * HW2;
    float s = scale[c], h = shift[c];
    for (int i = threadIdx.x; i < HW2; i += 256)
        ap[i] = fmaxf(fmaf(rp[i], s, h), 0.f);
}

// ---------------- FC1: one block per (j, b), float4 ----------------
__global__ __launch_bounds__(256) void fc1_kernel(
        const float* __restrict__ act3,   // [B][6272] activated
        const float* __restrict__ fc1w,   // [64][6272]
        const float* __restrict__ fc1b,
        float* __restrict__ h) {          // [B][64]
    const int FLAT4 = 6272 / 4;
    int j = blockIdx.x >> 5;
    int b = blockIdx.x & 31;
    const float4* ip = (const float4*)(act3 + (size_t)b * 6272);
    const float4* wp = (const float4*)(fc1w + (size_t)j * 6272);
    float s = 0.f;
    for (int i = threadIdx.x; i < FLAT4; i += 256) {
        float4 xv = ip[i], wv = wp[i];
        s = fmaf(xv.x, wv.x, s); s = fmaf(xv.y, wv.y, s);
        s = fmaf(xv.z, wv.z, s); s = fmaf(xv.w, wv.w, s);
    }
    #pragma unroll
    for (int o = 32; o > 0; o >>= 1) s += __shfl_down(s, o, 64);
    __shared__ float red[4];
    if ((threadIdx.x & 63) == 0) red[threadIdx.x >> 6] = s;
    __syncthreads();
    if (threadIdx.x == 0) {
        float t = red[0] + red[1] + red[2] + red[3];
        h[b * 64 + j] = fmaxf(t + fc1b[j], 0.f);
    }
}

// ---------------- FC2 + sigmoid ----------------
__global__ __launch_bounds__(64) void fc2_kernel(
        const float* __restrict__ h, const float* __restrict__ fc2w,
        const float* __restrict__ fc2b, float* __restrict__ outp) {
    int b = blockIdx.x;
    float v = h[b * 64 + threadIdx.x] * fc2w[threadIdx.x];
    #pragma unroll
    for (int o = 32; o > 0; o >>= 1) v += __shfl_down(v, o, 64);
    if (threadIdx.x == 0) outp[b] = 1.f / (1.f + expf(-(v + fc2b[0])));
}

// ---------------- Launch ----------------
extern "C" void kernel_launch(void* const* d_in, const int* in_sizes, int n_in,
                              void* d_out, int out_size, void* d_ws, size_t ws_size,
                              hipStream_t stream) {
    const float* x       = (const float*)d_in[0];
    const float* conv1_w = (const float*)d_in[1];
    const float* conv1_b = (const float*)d_in[2];
    const float* bn1_g   = (const float*)d_in[3];
    const float* bn1_b   = (const float*)d_in[4];
    const float* conv2_w = (const float*)d_in[5];
    const float* conv2_b = (const float*)d_in[6];
    const float* bn2_g   = (const float*)d_in[7];
    const float* bn2_b   = (const float*)d_in[8];
    const float* conv3_w = (const float*)d_in[9];
    const float* conv3_b = (const float*)d_in[10];
    const float* bn3_g   = (const float*)d_in[11];
    const float* bn3_b   = (const float*)d_in[12];
    const float* fc1_w   = (const float*)d_in[13];
    const float* fc1_b   = (const float*)d_in[14];
    const float* fc2_w   = (const float*)d_in[15];
    const float* fc2_b   = (const float*)d_in[16];
    float* out = (float*)d_out;

    float* ws = (float*)d_ws;
    size_t off = 0;
    float* layout = ws + off; off += (size_t)BB * NREC * HW * HW;   // 8,128,512
    float* out1   = ws + off; off += (size_t)BB * 64  * 31 * 31;
    float* out2   = ws + off; off += (size_t)BB * 128 * 15 * 15;
    float* out3   = ws + off; off += (size_t)BB * 128 * 7 * 7;
    float* psum1  = ws + off; off += 64 * 128;
    float* psq1   = ws + off; off += 64 * 128;
    float* psum2  = ws + off; off += 128 * 32;
    float* psq2   = ws + off; off += 128 * 32;
    float* psum3  = ws + off; off += 128 * 32;
    float* psq3   = ws + off; off += 128 * 32;
    float* scale1 = ws + off; off += 64;
    float* shift1 = ws + off; off += 64;
    float* scale2 = ws + off; off += 128;
    float* shift2 = ws + off; off += 128;
    float* scale3 = ws + off; off += 128;
    float* shift3 = ws + off; off += 128;
    float* hbuf   = ws + off; off += BB * 64;
    // activated buffers alias the layout region (layout is dead after conv1)
    float* act1 = layout;                 // 1,968,128 floats
    float* act2 = layout + 2200000;       //   921,600 floats
    float* act3 = layout + 3400000;       //   200,704 floats

    render_kernel<<<BB * NREC, 256, 0, stream>>>(x, layout);

    // conv1: 63->31, 2x2 tiles of 16x16, COG=8, cg-major -> grid 8*128 = 1024
    convd_kernel<64, 64, 63, 31, 16, 16, 256, 8>
        <<<8 * 32 * 4, 256, 0, stream>>>(layout, conv1_w, conv1_b,
                                         out1, psum1, psq1);
    stats_kernel<<<1, 64, 0, stream>>>(psum1, psq1, bn1_g, bn1_b, scale1, shift1,
                                       64, 32 * 4, (float)(BB * 31 * 31));
    apply_kernel<<<BB * 64, 256, 0, stream>>>(out1, scale1, shift1, act1, 64, 961);

    // conv2: 31->15, single tile, COG=4, cg-major -> grid 32*32 = 1024
    convd_kernel<64, 128, 31, 15, 15, 15, 256, 4>
        <<<32 * 32, 256, 0, stream>>>(act1, conv2_w, conv2_b,
                                      out2, psum2, psq2);
    stats_kernel<<<1, 128, 0, stream>>>(psum2, psq2, bn2_g, bn2_b, scale2, shift2,
                                        128, 32, (float)(BB * 15 * 15));
    apply_kernel<<<BB * 128, 256, 0, stream>>>(out2, scale2, shift2, act2, 128, 225);

    // conv3: 15->7, wave-split CIN, COG=8, cg-major -> grid 16*32 = 512
    conv3_kernel<<<16 * 32, 256, 0, stream>>>(act2, conv3_w, conv3_b,
                                              out3, psum3, psq3);
    stats_kernel<<<1, 128, 0, stream>>>(psum3, psq3, bn3_g, bn3_b, scale3, shift3,
                                        128, 32, (float)(BB * 7 * 7));
    apply_kernel<<<BB * 128, 256, 0, stream>>>(out3, scale3, shift3, act3, 128, 49);

    fc1_kernel<<<64 * 32, 256, 0, stream>>>(act3, fc1_w, fc1_b, hbuf);
    fc2_kernel<<<BB, 64, 0, stream>>>(hbuf, fc2_w, fc2_b, out);
}